// Round 8
// baseline (158.607 us; speedup 1.0000x reference)
//
#include <hip/hip_runtime.h>
#include <hip/hip_bf16.h>
#include <stdint.h>

typedef unsigned short ushort_t;
typedef unsigned long long u64;
typedef __attribute__((ext_vector_type(8))) short short8;   // 8 bf16 (4 VGPRs)
typedef __attribute__((ext_vector_type(4))) float f32x4;

#define N_NODES 384
#define HF      512
#define IT      6         // i-rows per attention block: 64 tiles x 8 heads = 512

__device__ inline ushort_t f2bf(float f) {
  __hip_bfloat16 b = __float2bfloat16(f);
  return *reinterpret_cast<ushort_t*>(&b);
}
__device__ inline float bf2f_u(ushort_t u) {
  union { float f; uint32_t i; } v; v.i = ((uint32_t)u) << 16; return v.f;
}
__device__ inline short8 pack8(const float* s) {
  short8 r;
#pragma unroll
  for (int j = 0; j < 8; ++j) r[j] = (short)f2bf(s[j]);
  return r;
}

// ---------------------------------------------------------------------------
// Kernel 1/3: dual GEMM, raw fp32 inputs, in-register bf16 cvt.
// G[m][n] = sum_k X[m][k]*W[k][n], n in [0,1024), W = [WL | WR] fp32.
//  n <  512 (gl): glb bf16 [m][n]
//  n >= 512 (gr): G fp32 [m][512+n'] and grT bf16 [n'][m] (k-contig)
// grid (24,16), 256 thr = 4 waves; wave computes 16m x 16n  (1536 waves,
// ~1.5/SIMD device-wide -> TLP hides the strided-B L2 latency).
// Layer 0 extra: adjacency bitmasks (by==0 blocks).
// ---------------------------------------------------------------------------
__global__ __launch_bounds__(256) void gemm_direct(
    const float* __restrict__ X, const float* __restrict__ WL,
    const float* __restrict__ WR, float* __restrict__ G,
    ushort_t* __restrict__ glb, ushort_t* __restrict__ grT,
    const int* __restrict__ adj, u64* __restrict__ mbits)
{
  const int t = threadIdx.x, wave = t >> 6, lane = t & 63;
  const int lm = lane & 15, q = lane >> 4;
  const int m0 = blockIdx.x * 16;
  const int n0 = (blockIdx.y * 4 + wave) * 16;
  const float* Wp = (n0 < 512) ? (WL + n0) : (WR + (n0 - 512));
  const float* Arow = X + (m0 + lm) * HF;

  f32x4 acc = {0.f, 0.f, 0.f, 0.f};
#pragma unroll 4
  for (int kc = 0; kc < 16; ++kc) {
    const int kbase = kc * 32 + q * 8;
    float4 a0 = *(const float4*)(Arow + kbase);
    float4 a1 = *(const float4*)(Arow + kbase + 4);
    float av8[8] = {a0.x, a0.y, a0.z, a0.w, a1.x, a1.y, a1.z, a1.w};
    short8 af = pack8(av8);
    float bf8[8];
#pragma unroll
    for (int j = 0; j < 8; ++j) bf8[j] = Wp[(kbase + j) * HF + lm];
    short8 b = pack8(bf8);
    acc = __builtin_amdgcn_mfma_f32_16x16x32_bf16(af, b, acc, 0, 0, 0);
  }
  if (n0 < 512) {
#pragma unroll
    for (int r = 0; r < 4; ++r)
      glb[(m0 + q * 4 + r) * HF + n0 + lm] = f2bf(acc[r]);
  } else {
#pragma unroll
    for (int r = 0; r < 4; ++r)
      G[(m0 + q * 4 + r) * 1024 + n0 + lm] = acc[r];
    int c0 = n0 - 512;
    uint2 p0;
    p0.x = (uint32_t)f2bf(acc[0]) | ((uint32_t)f2bf(acc[1]) << 16);
    p0.y = (uint32_t)f2bf(acc[2]) | ((uint32_t)f2bf(acc[3]) << 16);
    *(uint2*)&grT[(c0 + lm) * 384 + m0 + q * 4] = p0;
  }
  // layer-0 only: adjacency bitmasks (self-loop OR'd in), by==0 blocks
  if (adj != nullptr && blockIdx.y == 0) {
    int rbase = (blockIdx.x * 4 + wave) * 4;
    for (int rr = 0; rr < 4; ++rr) {
      int row = rbase + rr;
#pragma unroll
      for (int w = 0; w < 6; ++w) {
        int j = w * 64 + lane;
        u64 m = __ballot(adj[row * N_NODES + j] != 0 || row == j);
        if (lane == 0) mbits[row * 6 + w] = m;
      }
    }
  }
}

// ---------------------------------------------------------------------------
// Kernel 2/4: fused GATv2 attention. Block = (6-row i-tile, head), 384 thr.
// grid (64, 8) = 512 blocks = 2 blocks/CU -> 12 waves/CU (3/SIMD TLP).
// Thread t == source node j. leaky(z) = 0.6 z + 0.4 |z|.
// Phase 1: gl_j in 64 VGPRs; a[f] and gr[il][f] are wave-uniform -> SGPRs
//   (s_load); inner op = v_add(s,v) + v_fma(s,|z|,acc). ~100 VGPRs total.
// Phase 2 softmax -> P bf16 LDS. Phase 3 MFMA P @ grT. Epilogue fused.
// LAYER 0: ELU + x residual -> xcur fp32. LAYER 1: + xcur -> out fp32.
// ---------------------------------------------------------------------------
template <int LAYER>
__global__ __launch_bounds__(384) void attn_fused(
    const float* __restrict__ G, const ushort_t* __restrict__ glb,
    const ushort_t* __restrict__ grT, const u64* __restrict__ mbits,
    const float* __restrict__ resid_in, const float* __restrict__ avec,
    float* __restrict__ xcur_out, float* __restrict__ f_out)
{
  // s_gl [384][72] bf16 = 55296 B, barrier-aliased with
  // { s_e fp32 6x384 (9216) + s_pb bf16 16x392 (12544) = 21760 }.
  __shared__ __align__(16) char smem[55296];
  ushort_t (*s_gl)[72]     = (ushort_t(*)[72])smem;
  float    (*s_e)[N_NODES] = (float(*)[N_NODES])smem;
  ushort_t (*s_pb)[392]    = (ushort_t(*)[392])(smem + 9216);
  __shared__ float s_bri[IT];
  __shared__ u64   s_mask[IT][6];

  const int t = threadIdx.x;
  const int i0 = blockIdx.x * IT, h = blockIdx.y;
  const int lane = t & 63, wave = t >> 6;

  // -- phase 0a: masks (36 u64) + bri dot (threads 128..224) --
  if (t < 36) ((u64*)s_mask)[t] = mbits[i0 * 6 + t];
  if (t >= 128 && t < 224) {
    int u = t - 128, il = u >> 4, fg = u & 15;
    float4 g4 = *(const float4*)(G + (i0 + il) * 1024 + 512 + h * 64 + fg * 4);
    float4 a4 = *(const float4*)(avec + fg * 4);
    float s = a4.x * g4.x + a4.y * g4.y + a4.z * g4.z + a4.w * g4.w;
    s += __shfl_xor(s, 1); s += __shfl_xor(s, 2);
    s += __shfl_xor(s, 4); s += __shfl_xor(s, 8);
    if (fg == 0) s_bri[il] = s;
  }
  // -- phase 0b: stage all 384 gl rows (bf16) coalesced into LDS --
#pragma unroll
  for (int rep = 0; rep < 8; ++rep) {
    int idx = rep * 384 + t, row = idx >> 3, c = idx & 7;
    *(short8*)&s_gl[row][c * 8] =
        *(const short8*)&glb[row * HF + h * 64 + c * 8];
  }
  __syncthreads();

  // -- own j-row -> 64 VGPRs (fp32) --
  float gl[64];
  {
    const short8* rowp = (const short8*)&s_gl[t][0];
#pragma unroll
    for (int c = 0; c < 8; ++c) {
      short8 v = rowp[c];
#pragma unroll
      for (int u2 = 0; u2 < 8; ++u2)
        gl[c * 8 + u2] = bf2f_u((ushort_t)v[u2]);
    }
  }
  float accl = 0.f;
#pragma unroll
  for (int f = 0; f < 64; ++f) accl += avec[f] * gl[f];   // a: SGPR
  __syncthreads();   // s_gl dead; region becomes s_e / s_pb

  // -- phase 1: scores; gr + a stay in SGPRs (uniform), gl in VGPRs --
  const int jw = t >> 6, jb = t & 63;
#pragma unroll
  for (int il = 0; il < IT; ++il) {
    const float* __restrict__ grp = G + (i0 + il) * 1024 + 512 + h * 64;
    float acc = 0.f;
#pragma unroll
    for (int f = 0; f < 64; ++f)
      acc += avec[f] * fabsf(gl[f] + grp[f]);   // v_add(s,v); v_fma(s,|z|)
    bool m = (s_mask[il][jw] >> jb) & 1;
    float e = 0.6f * (accl + s_bri[il]) + 0.4f * acc;
    s_e[il][t] = m ? e : -1e30f;
  }
#pragma unroll
  for (int r10 = 0; r10 < 10; ++r10) s_pb[IT + r10][t] = 0;  // P rows 6..15
  __syncthreads();

  // -- phase 2: softmax over j per row (wave = row); write P bf16 --
  {
    int il = wave;
    float v[6];
    float mx = -1e30f;
#pragma unroll
    for (int c = 0; c < 6; ++c) { v[c] = s_e[il][lane + 64 * c]; mx = fmaxf(mx, v[c]); }
#pragma unroll
    for (int off = 32; off; off >>= 1) mx = fmaxf(mx, __shfl_xor(mx, off));
    float sum = 0.f;
#pragma unroll
    for (int c = 0; c < 6; ++c) { v[c] = __expf(v[c] - mx); sum += v[c]; }
#pragma unroll
    for (int off = 32; off; off >>= 1) sum += __shfl_xor(sum, off);
    float inv = 1.0f / sum;
#pragma unroll
    for (int c = 0; c < 6; ++c) s_pb[il][lane + 64 * c] = f2bf(v[c] * inv);
  }
  __syncthreads();

  // -- phase 3: MFMA aggregation out[6 i][64 f] = P[6][384] @ gr[384][64] --
  if (wave < 4) {
    const int lm = lane & 15, q = lane >> 4;
    const int f0 = wave * 16;
    const ushort_t* Brow = grT + (h * 64 + f0 + lm) * 384;
    f32x4 acc = {0.f, 0.f, 0.f, 0.f};
#pragma unroll
    for (int kc = 0; kc < 12; ++kc) {
      short8 af = *(const short8*)&s_pb[lm][kc * 32 + q * 8];
      short8 bf = *(const short8*)&Brow[kc * 32 + q * 8];
      acc = __builtin_amdgcn_mfma_f32_16x16x32_bf16(af, bf, acc, 0, 0, 0);
    }
#pragma unroll
    for (int r = 0; r < 4; ++r) {
      if (q * 4 + r < IT) {                       // D rows 0..5
        int i = i0 + q * 4 + r;
        int off = i * HF + h * 64 + f0 + lm;
        float o = acc[r];
        if (LAYER == 0) {
          float oe = (o > 0.f) ? o : (__expf(o) - 1.f);   // ELU
          xcur_out[off] = resid_in[off] + oe;   // fp32 residual for layer 1
        } else {
          f_out[off] = resid_in[off] + o;       // final output, fp32
        }
      }
    }
  }
}

// ---------------------------------------------------------------------------
extern "C" void kernel_launch(void* const* d_in, const int* in_sizes, int n_in,
                              void* d_out, int out_size, void* d_ws, size_t ws_size,
                              hipStream_t stream) {
  const float* x   = (const float*)d_in[0];
  const int*   adj = (const int*)d_in[1];
  const float* Wl0 = (const float*)d_in[2];
  const float* Wr0 = (const float*)d_in[3];
  const float* a0  = (const float*)d_in[4];
  const float* Wl1 = (const float*)d_in[5];
  const float* Wr1 = (const float*)d_in[6];
  const float* a1  = (const float*)d_in[7];
  float* out = (float*)d_out;

  char* ws = (char*)d_ws;
  float*    G    = (float*)   (ws + 0L);            // 1.5 MB (gr half used)
  ushort_t* grT  = (ushort_t*)(ws + (2L << 20));    // 384 KB gr^T bf16
  ushort_t* glb  = (ushort_t*)(ws + (3L << 20));    // 384 KB gl bf16
  u64*      mbits= (u64*)     (ws + (4L << 20));    // 18 KB adjacency bits
  float*    xcur = (float*)   (ws + (5L << 20));    // 768 KB fp32 residual

  gemm_direct<<<dim3(24, 16), 256, 0, stream>>>(x, Wl0, Wr0, G, glb, grT,
                                                adj, mbits);
  attn_fused<0><<<dim3(64, 8), 384, 0, stream>>>(G, glb, grT, mbits, x, a0,
                                                 xcur, nullptr);
  gemm_direct<<<dim3(24, 16), 256, 0, stream>>>(xcur, Wl1, Wr1, G, glb, grT,
                                                nullptr, nullptr);
  attn_fused<1><<<dim3(64, 8), 384, 0, stream>>>(G, glb, grT, mbits, xcur, a1,
                                                 nullptr, out);
}

// Round 9
// 130.094 us; speedup vs baseline: 1.2192x; 1.2192x over previous
//
#include <hip/hip_runtime.h>
#include <hip/hip_bf16.h>
#include <stdint.h>

typedef unsigned short ushort_t;
typedef unsigned long long u64;
typedef __attribute__((ext_vector_type(8))) short short8;   // 8 bf16 (4 VGPRs)
typedef __attribute__((ext_vector_type(4))) float f32x4;

#define N_NODES 384
#define HF      512
#define IT      6         // i-rows per attention block: 64 tiles x 8 heads = 512

__device__ inline ushort_t f2bf(float f) {
  __hip_bfloat16 b = __float2bfloat16(f);
  return *reinterpret_cast<ushort_t*>(&b);
}
__device__ inline float bf2f_u(ushort_t u) {
  union { float f; uint32_t i; } v; v.i = ((uint32_t)u) << 16; return v.f;
}
__device__ inline short8 pack8(const float* s) {
  short8 r;
#pragma unroll
  for (int j = 0; j < 8; ++j) r[j] = (short)f2bf(s[j]);
  return r;
}

// ---------------------------------------------------------------------------
// Kernel 1/3: dual GEMM, raw fp32 inputs, in-register bf16 cvt (== R7).
// G[m][n] = sum_k X[m][k]*W[k][n], n in [0,1024), W = [WL | WR] fp32.
//  n <  512 (gl): glb bf16 [m][n]
//  n >= 512 (gr): G fp32 [m][512+n'] and grT bf16 [n'][m] (k-contig)
// grid (24, 8), 256 threads = 4 waves; wave computes 16m x 32n.
// Layer 0 extra: adjacency bitmasks (by==0 blocks).
// ---------------------------------------------------------------------------
__global__ __launch_bounds__(256) void gemm_direct(
    const float* __restrict__ X, const float* __restrict__ WL,
    const float* __restrict__ WR, float* __restrict__ G,
    ushort_t* __restrict__ glb, ushort_t* __restrict__ grT,
    const int* __restrict__ adj, u64* __restrict__ mbits)
{
  const int t = threadIdx.x, wave = t >> 6, lane = t & 63;
  const int lm = lane & 15, q = lane >> 4;
  const int m0 = blockIdx.x * 16;
  const int n0 = (blockIdx.y * 4 + wave) * 32;
  const float* Wp = (n0 < 512) ? (WL + n0) : (WR + (n0 - 512));
  const float* Arow = X + (m0 + lm) * HF;

  f32x4 acc0 = {0.f, 0.f, 0.f, 0.f};
  f32x4 acc1 = {0.f, 0.f, 0.f, 0.f};
#pragma unroll 4
  for (int kc = 0; kc < 16; ++kc) {
    const int kbase = kc * 32 + q * 8;
    float4 a0 = *(const float4*)(Arow + kbase);
    float4 a1 = *(const float4*)(Arow + kbase + 4);
    float av8[8] = {a0.x, a0.y, a0.z, a0.w, a1.x, a1.y, a1.z, a1.w};
    short8 af = pack8(av8);
    float b0f[8], b1f[8];
#pragma unroll
    for (int j = 0; j < 8; ++j) {
      const float* r = Wp + (kbase + j) * HF;   // 64 lanes -> ~4 lines/instr
      b0f[j] = r[lm];
      b1f[j] = r[16 + lm];
    }
    short8 b0 = pack8(b0f);
    short8 b1 = pack8(b1f);
    acc0 = __builtin_amdgcn_mfma_f32_16x16x32_bf16(af, b0, acc0, 0, 0, 0);
    acc1 = __builtin_amdgcn_mfma_f32_16x16x32_bf16(af, b1, acc1, 0, 0, 0);
  }
  if (n0 < 512) {
#pragma unroll
    for (int r = 0; r < 4; ++r) {
      int m = m0 + q * 4 + r;
      glb[m * HF + n0 + lm]      = f2bf(acc0[r]);
      glb[m * HF + n0 + 16 + lm] = f2bf(acc1[r]);
    }
  } else {
#pragma unroll
    for (int r = 0; r < 4; ++r) {
      int m = m0 + q * 4 + r;
      G[m * 1024 + n0 + lm]      = acc0[r];
      G[m * 1024 + n0 + 16 + lm] = acc1[r];
    }
    int c0 = n0 - 512;
    uint2 p0, p1;
    p0.x = (uint32_t)f2bf(acc0[0]) | ((uint32_t)f2bf(acc0[1]) << 16);
    p0.y = (uint32_t)f2bf(acc0[2]) | ((uint32_t)f2bf(acc0[3]) << 16);
    p1.x = (uint32_t)f2bf(acc1[0]) | ((uint32_t)f2bf(acc1[1]) << 16);
    p1.y = (uint32_t)f2bf(acc1[2]) | ((uint32_t)f2bf(acc1[3]) << 16);
    *(uint2*)&grT[(c0 + lm) * 384 + m0 + q * 4]      = p0;
    *(uint2*)&grT[(c0 + 16 + lm) * 384 + m0 + q * 4] = p1;
  }
  // layer-0 only: adjacency bitmasks (self-loop OR'd in), by==0 blocks
  if (adj != nullptr && blockIdx.y == 0) {
    int rbase = (blockIdx.x * 4 + wave) * 4;
    for (int rr = 0; rr < 4; ++rr) {
      int row = rbase + rr;
#pragma unroll
      for (int w = 0; w < 6; ++w) {
        int j = w * 64 + lane;
        u64 m = __ballot(adj[row * N_NODES + j] != 0 || row == j);
        if (lane == 0) mbits[row * 6 + w] = m;
      }
    }
  }
}

// ---------------------------------------------------------------------------
// Kernel 2/4: fused GATv2 attention. Block = (6-row i-tile, head), 384 thr.
// grid (64, 8) = 512 blocks = 2 blocks/CU (12 waves/CU). Phase-1 code is
// R7's proven form: gl_j + avec in VGPRs, gr via per-lane float4 broadcast
// loads (uniform addr -> 1 line/instr), scores straight to LDS.
// Phase 2 softmax (wave = row) -> P bf16 LDS. Phase 3 MFMA P @ grT.
// LAYER 0: ELU + x residual -> xcur fp32. LAYER 1: + xcur -> out fp32.
// ---------------------------------------------------------------------------
template <int LAYER>
__global__ __launch_bounds__(384) void attn_fused(
    const float* __restrict__ G, const ushort_t* __restrict__ glb,
    const ushort_t* __restrict__ grT, const u64* __restrict__ mbits,
    const float* __restrict__ resid_in, const float* __restrict__ avec,
    float* __restrict__ xcur_out, float* __restrict__ f_out)
{
  // s_gl [384][72] bf16 = 55296 B, barrier-aliased with
  // { s_e fp32 6x384 (9216) + s_pb bf16 16x392 (12544) = 21760 }.
  __shared__ __align__(16) char smem[55296];
  ushort_t (*s_gl)[72]     = (ushort_t(*)[72])smem;
  float    (*s_e)[N_NODES] = (float(*)[N_NODES])smem;
  ushort_t (*s_pb)[392]    = (ushort_t(*)[392])(smem + 9216);
  __shared__ float s_bri[IT];
  __shared__ u64   s_mask[IT][6];

  const int t = threadIdx.x;
  const int i0 = blockIdx.x * IT, h = blockIdx.y;
  const int lane = t & 63, wave = t >> 6;

  // -- phase 0a: masks (36 u64) + bri dot (threads 128..224) --
  if (t < 36) ((u64*)s_mask)[t] = mbits[i0 * 6 + t];
  if (t >= 128 && t < 224) {
    int u = t - 128, il = u >> 4, fg = u & 15;
    float4 g4 = *(const float4*)(G + (i0 + il) * 1024 + 512 + h * 64 + fg * 4);
    float4 a4 = *(const float4*)(avec + fg * 4);
    float s = a4.x * g4.x + a4.y * g4.y + a4.z * g4.z + a4.w * g4.w;
    s += __shfl_xor(s, 1); s += __shfl_xor(s, 2);
    s += __shfl_xor(s, 4); s += __shfl_xor(s, 8);
    if (fg == 0) s_bri[il] = s;
  }
  // -- phase 0b: stage all 384 gl rows (bf16) coalesced into LDS --
#pragma unroll
  for (int rep = 0; rep < 8; ++rep) {
    int idx = rep * 384 + t, row = idx >> 3, c = idx & 7;
    *(short8*)&s_gl[row][c * 8] =
        *(const short8*)&glb[row * HF + h * 64 + c * 8];
  }
  __syncthreads();

  // -- own j-row -> 64 VGPRs; avec -> 64 VGPRs --
  float gl[64], av[64];
  {
    const short8* rowp = (const short8*)&s_gl[t][0];
#pragma unroll
    for (int c = 0; c < 8; ++c) {
      short8 v = rowp[c];
#pragma unroll
      for (int u2 = 0; u2 < 8; ++u2)
        gl[c * 8 + u2] = bf2f_u((ushort_t)v[u2]);
    }
#pragma unroll
    for (int c = 0; c < 16; ++c) {
      float4 a4 = ((const float4*)avec)[c];
      av[c * 4] = a4.x; av[c * 4 + 1] = a4.y;
      av[c * 4 + 2] = a4.z; av[c * 4 + 3] = a4.w;
    }
  }
  float accl = 0.f;
#pragma unroll
  for (int f = 0; f < 64; ++f) accl += av[f] * gl[f];
  __syncthreads();   // s_gl dead; region becomes s_e / s_pb

  // -- phase 1: scores, written straight to LDS (no private arrays) --
  const int jw = t >> 6, jb = t & 63;
#pragma unroll
  for (int il = 0; il < IT; ++il) {
    const float4* gr4 = (const float4*)(G + (i0 + il) * 1024 + 512 + h * 64);
    float acc = 0.f;
#pragma unroll
    for (int c = 0; c < 16; ++c) {
      float4 g4 = gr4[c];
      acc += av[c * 4]     * fabsf(gl[c * 4]     + g4.x);
      acc += av[c * 4 + 1] * fabsf(gl[c * 4 + 1] + g4.y);
      acc += av[c * 4 + 2] * fabsf(gl[c * 4 + 2] + g4.z);
      acc += av[c * 4 + 3] * fabsf(gl[c * 4 + 3] + g4.w);
    }
    bool m = (s_mask[il][jw] >> jb) & 1;
    float e = 0.6f * (accl + s_bri[il]) + 0.4f * acc;
    s_e[il][t] = m ? e : -1e30f;
  }
#pragma unroll
  for (int r10 = 0; r10 < 10; ++r10) s_pb[IT + r10][t] = 0;  // P rows 6..15
  __syncthreads();

  // -- phase 2: softmax over j per row (wave = row); write P bf16 --
  {
    int il = wave;
    float v[6];
    float mx = -1e30f;
#pragma unroll
    for (int c = 0; c < 6; ++c) { v[c] = s_e[il][lane + 64 * c]; mx = fmaxf(mx, v[c]); }
#pragma unroll
    for (int off = 32; off; off >>= 1) mx = fmaxf(mx, __shfl_xor(mx, off));
    float sum = 0.f;
#pragma unroll
    for (int c = 0; c < 6; ++c) { v[c] = __expf(v[c] - mx); sum += v[c]; }
#pragma unroll
    for (int off = 32; off; off >>= 1) sum += __shfl_xor(sum, off);
    float inv = 1.0f / sum;
#pragma unroll
    for (int c = 0; c < 6; ++c) s_pb[il][lane + 64 * c] = f2bf(v[c] * inv);
  }
  __syncthreads();

  // -- phase 3: MFMA aggregation out[6 i][64 f] = P[6][384] @ gr[384][64] --
  if (wave < 4) {
    const int lm = lane & 15, q = lane >> 4;
    const int f0 = wave * 16;
    const ushort_t* Brow = grT + (h * 64 + f0 + lm) * 384;
    f32x4 acc = {0.f, 0.f, 0.f, 0.f};
#pragma unroll
    for (int kc = 0; kc < 12; ++kc) {
      short8 af = *(const short8*)&s_pb[lm][kc * 32 + q * 8];
      short8 bf = *(const short8*)&Brow[kc * 32 + q * 8];
      acc = __builtin_amdgcn_mfma_f32_16x16x32_bf16(af, bf, acc, 0, 0, 0);
    }
#pragma unroll
    for (int r = 0; r < 4; ++r) {
      if (q * 4 + r < IT) {                       // D rows 0..5
        int i = i0 + q * 4 + r;
        int off = i * HF + h * 64 + f0 + lm;
        float o = acc[r];
        if (LAYER == 0) {
          float oe = (o > 0.f) ? o : (__expf(o) - 1.f);   // ELU
          xcur_out[off] = resid_in[off] + oe;   // fp32 residual for layer 1
        } else {
          f_out[off] = resid_in[off] + o;       // final output, fp32
        }
      }
    }
  }
}

// ---------------------------------------------------------------------------
extern "C" void kernel_launch(void* const* d_in, const int* in_sizes, int n_in,
                              void* d_out, int out_size, void* d_ws, size_t ws_size,
                              hipStream_t stream) {
  const float* x   = (const float*)d_in[0];
  const int*   adj = (const int*)d_in[1];
  const float* Wl0 = (const float*)d_in[2];
  const float* Wr0 = (const float*)d_in[3];
  const float* a0  = (const float*)d_in[4];
  const float* Wl1 = (const float*)d_in[5];
  const float* Wr1 = (const float*)d_in[6];
  const float* a1  = (const float*)d_in[7];
  float* out = (float*)d_out;

  char* ws = (char*)d_ws;
  float*    G    = (float*)   (ws + 0L);            // 1.5 MB (gr half used)
  ushort_t* grT  = (ushort_t*)(ws + (2L << 20));    // 384 KB gr^T bf16
  ushort_t* glb  = (ushort_t*)(ws + (3L << 20));    // 384 KB gl bf16
  u64*      mbits= (u64*)     (ws + (4L << 20));    // 18 KB adjacency bits
  float*    xcur = (float*)   (ws + (5L << 20));    // 768 KB fp32 residual

  gemm_direct<<<dim3(24, 8), 256, 0, stream>>>(x, Wl0, Wr0, G, glb, grT,
                                               adj, mbits);
  attn_fused<0><<<dim3(64, 8), 384, 0, stream>>>(G, glb, grT, mbits, x, a0,
                                                 xcur, nullptr);
  gemm_direct<<<dim3(24, 8), 256, 0, stream>>>(xcur, Wl1, Wr1, G, glb, grT,
                                               nullptr, nullptr);
  attn_fused<1><<<dim3(64, 8), 384, 0, stream>>>(G, glb, grT, mbits, xcur, a1,
                                                 nullptr, out);
}

// Round 10
// 118.772 us; speedup vs baseline: 1.3354x; 1.0953x over previous
//
#include <hip/hip_runtime.h>
#include <hip/hip_bf16.h>
#include <stdint.h>

typedef unsigned short ushort_t;
typedef unsigned long long u64;
typedef __attribute__((ext_vector_type(8))) short short8;   // 8 bf16 (4 VGPRs)
typedef __attribute__((ext_vector_type(4))) float f32x4;

#define N_NODES 384
#define HF      512
#define IT      12        // i-rows per attention block: 32 tiles x 8 heads = 256

__device__ inline ushort_t f2bf(float f) {
  __hip_bfloat16 b = __float2bfloat16(f);
  return *reinterpret_cast<ushort_t*>(&b);
}
__device__ inline float bf2f_u(ushort_t u) {
  union { float f; uint32_t i; } v; v.i = ((uint32_t)u) << 16; return v.f;
}
__device__ inline short8 pack8(const float* s) {
  short8 r;
#pragma unroll
  for (int j = 0; j < 8; ++j) r[j] = (short)f2bf(s[j]);
  return r;
}

// ---------------------------------------------------------------------------
// Kernel 1/3: dual GEMM, raw fp32 inputs, in-register bf16 cvt (== R7).
// G[m][n] = sum_k X[m][k]*W[k][n], n in [0,1024), W = [WL | WR] fp32.
//  n <  512 (gl): glb bf16 [m][n]
//  n >= 512 (gr): G fp32 [m][512+n'] and grT bf16 [n'][m] (k-contig)
// grid (24, 8), 256 threads = 4 waves; wave computes 16m x 32n.
// Layer 0 extra: adjacency bitmasks (by==0 blocks).
// ---------------------------------------------------------------------------
__global__ __launch_bounds__(256) void gemm_direct(
    const float* __restrict__ X, const float* __restrict__ WL,
    const float* __restrict__ WR, float* __restrict__ G,
    ushort_t* __restrict__ glb, ushort_t* __restrict__ grT,
    const int* __restrict__ adj, u64* __restrict__ mbits)
{
  const int t = threadIdx.x, wave = t >> 6, lane = t & 63;
  const int lm = lane & 15, q = lane >> 4;
  const int m0 = blockIdx.x * 16;
  const int n0 = (blockIdx.y * 4 + wave) * 32;
  const float* Wp = (n0 < 512) ? (WL + n0) : (WR + (n0 - 512));
  const float* Arow = X + (m0 + lm) * HF;

  f32x4 acc0 = {0.f, 0.f, 0.f, 0.f};
  f32x4 acc1 = {0.f, 0.f, 0.f, 0.f};
#pragma unroll 4
  for (int kc = 0; kc < 16; ++kc) {
    const int kbase = kc * 32 + q * 8;
    float4 a0 = *(const float4*)(Arow + kbase);
    float4 a1 = *(const float4*)(Arow + kbase + 4);
    float av8[8] = {a0.x, a0.y, a0.z, a0.w, a1.x, a1.y, a1.z, a1.w};
    short8 af = pack8(av8);
    float b0f[8], b1f[8];
#pragma unroll
    for (int j = 0; j < 8; ++j) {
      const float* r = Wp + (kbase + j) * HF;   // 64 lanes -> ~4 lines/instr
      b0f[j] = r[lm];
      b1f[j] = r[16 + lm];
    }
    short8 b0 = pack8(b0f);
    short8 b1 = pack8(b1f);
    acc0 = __builtin_amdgcn_mfma_f32_16x16x32_bf16(af, b0, acc0, 0, 0, 0);
    acc1 = __builtin_amdgcn_mfma_f32_16x16x32_bf16(af, b1, acc1, 0, 0, 0);
  }
  if (n0 < 512) {
#pragma unroll
    for (int r = 0; r < 4; ++r) {
      int m = m0 + q * 4 + r;
      glb[m * HF + n0 + lm]      = f2bf(acc0[r]);
      glb[m * HF + n0 + 16 + lm] = f2bf(acc1[r]);
    }
  } else {
#pragma unroll
    for (int r = 0; r < 4; ++r) {
      int m = m0 + q * 4 + r;
      G[m * 1024 + n0 + lm]      = acc0[r];
      G[m * 1024 + n0 + 16 + lm] = acc1[r];
    }
    int c0 = n0 - 512;
    uint2 p0, p1;
    p0.x = (uint32_t)f2bf(acc0[0]) | ((uint32_t)f2bf(acc0[1]) << 16);
    p0.y = (uint32_t)f2bf(acc0[2]) | ((uint32_t)f2bf(acc0[3]) << 16);
    p1.x = (uint32_t)f2bf(acc1[0]) | ((uint32_t)f2bf(acc1[1]) << 16);
    p1.y = (uint32_t)f2bf(acc1[2]) | ((uint32_t)f2bf(acc1[3]) << 16);
    *(uint2*)&grT[(c0 + lm) * 384 + m0 + q * 4]      = p0;
    *(uint2*)&grT[(c0 + 16 + lm) * 384 + m0 + q * 4] = p1;
  }
  // layer-0 only: adjacency bitmasks (self-loop OR'd in), by==0 blocks
  if (adj != nullptr && blockIdx.y == 0) {
    int rbase = (blockIdx.x * 4 + wave) * 4;
    for (int rr = 0; rr < 4; ++rr) {
      int row = rbase + rr;
#pragma unroll
      for (int w = 0; w < 6; ++w) {
        int j = w * 64 + lane;
        u64 m = __ballot(adj[row * N_NODES + j] != 0 || row == j);
        if (lane == 0) mbits[row * 6 + w] = m;
      }
    }
  }
}

// ---------------------------------------------------------------------------
// Kernel 2/4: fused GATv2 attention (R7 structure, async-DMA staging).
// Block = (12-row i-tile, head), 384 thr, grid (32,8) = 256 blocks = 1/CU.
// Staging: __builtin_amdgcn_global_load_lds width=16, XOR-swizzled chunks
// (slot (row,cl) holds global chunk cl^(row&7); unpad 128 B rows; unpack at
// slot cg^(t&7) -> conflict-free banks). DMA issued first, overlapped with
// mask/bri work, drained by the staging barrier.
// Phase 1: gl_j + avec in VGPRs, gr via per-wave-uniform float4 loads,
// scores straight to LDS. Phase 2 softmax -> P bf16. Phase 3 MFMA P @ grT.
// LAYER 0: ELU + x residual -> xcur fp32. LAYER 1: + xcur -> out fp32.
// ---------------------------------------------------------------------------
template <int LAYER>
__global__ __launch_bounds__(384) void attn_fused(
    const float* __restrict__ G, const ushort_t* __restrict__ glb,
    const ushort_t* __restrict__ grT, const u64* __restrict__ mbits,
    const float* __restrict__ resid_in, const float* __restrict__ avec,
    float* __restrict__ xcur_out, float* __restrict__ f_out)
{
  // s_gl [384][64] bf16 (unpadded, swizzled) = 49152 B, barrier-aliased with
  // { s_e fp32 12x384 (18432) + s_pb bf16 16x392 (12544) = 30976 }.
  __shared__ __align__(16) char smem[49152];
  ushort_t (*s_gl)[64]     = (ushort_t(*)[64])smem;
  float    (*s_e)[N_NODES] = (float(*)[N_NODES])smem;
  ushort_t (*s_pb)[392]    = (ushort_t(*)[392])(smem + 18432);
  __shared__ float s_bri[IT];
  __shared__ u64   s_mask[IT][6];

  const int t = threadIdx.x;
  const int i0 = blockIdx.x * IT, h = blockIdx.y;
  const int lane = t & 63, wave = t >> 6;

  // -- phase 0b first: issue async global->LDS DMA (8 x 16 B per thread) --
  // slot(row, cl) <- global chunk cg = cl ^ (row & 7); LDS byte = idx*16
  // (contiguous per lane: wave-uniform base + lane*16 -- DMA constraint).
#pragma unroll
  for (int rep = 0; rep < 8; ++rep) {
    int idx = rep * 384 + t, row = idx >> 3, cl = idx & 7;
    int cg = cl ^ (row & 7);
    const ushort_t* gsrc = glb + row * HF + h * 64 + cg * 8;
    __builtin_amdgcn_global_load_lds(
        (const __attribute__((address_space(1))) uint32_t*)gsrc,
        (__attribute__((address_space(3))) uint32_t*)(smem + idx * 16),
        16, 0, 0);
  }

  // -- phase 0a (overlapped with DMA): masks (72 u64) + bri dot --
  if (t < 72) ((u64*)s_mask)[t] = mbits[i0 * 6 + t];
  if (t >= 128 && t < 320) {
    int u = t - 128, il = u >> 4, fg = u & 15;
    float4 g4 = *(const float4*)(G + (i0 + il) * 1024 + 512 + h * 64 + fg * 4);
    float4 a4 = *(const float4*)(avec + fg * 4);
    float s = a4.x * g4.x + a4.y * g4.y + a4.z * g4.z + a4.w * g4.w;
    s += __shfl_xor(s, 1); s += __shfl_xor(s, 2);
    s += __shfl_xor(s, 4); s += __shfl_xor(s, 8);
    if (fg == 0) s_bri[il] = s;
  }
  __syncthreads();   // drains DMA (vmcnt) + phase 0a

  // -- own j-row -> 64 VGPRs (read chunk cg at slot cg^(t&7)); avec -> VGPRs --
  float gl[64], av[64];
  {
    const int sw = t & 7;
#pragma unroll
    for (int cg = 0; cg < 8; ++cg) {
      short8 v = *(const short8*)&s_gl[t][(cg ^ sw) * 8];
#pragma unroll
      for (int u2 = 0; u2 < 8; ++u2)
        gl[cg * 8 + u2] = bf2f_u((ushort_t)v[u2]);
    }
#pragma unroll
    for (int c = 0; c < 16; ++c) {
      float4 a4 = ((const float4*)avec)[c];
      av[c * 4] = a4.x; av[c * 4 + 1] = a4.y;
      av[c * 4 + 2] = a4.z; av[c * 4 + 3] = a4.w;
    }
  }
  float accl = 0.f;
#pragma unroll
  for (int f = 0; f < 64; ++f) accl += av[f] * gl[f];
  __syncthreads();   // s_gl dead; region becomes s_e / s_pb

  // -- phase 1: scores, written straight to LDS (no private arrays) --
  const int jw = t >> 6, jb = t & 63;
#pragma unroll
  for (int il = 0; il < IT; ++il) {
    const float4* gr4 = (const float4*)(G + (i0 + il) * 1024 + 512 + h * 64);
    float acc = 0.f;
#pragma unroll
    for (int c = 0; c < 16; ++c) {
      float4 g4 = gr4[c];
      acc += av[c * 4]     * fabsf(gl[c * 4]     + g4.x);
      acc += av[c * 4 + 1] * fabsf(gl[c * 4 + 1] + g4.y);
      acc += av[c * 4 + 2] * fabsf(gl[c * 4 + 2] + g4.z);
      acc += av[c * 4 + 3] * fabsf(gl[c * 4 + 3] + g4.w);
    }
    bool m = (s_mask[il][jw] >> jb) & 1;
    float e = 0.6f * (accl + s_bri[il]) + 0.4f * acc;
    s_e[il][t] = m ? e : -1e30f;
  }
#pragma unroll
  for (int r4 = 0; r4 < 4; ++r4) s_pb[IT + r4][t] = 0;  // zero P rows 12..15
  __syncthreads();

  // -- phase 2: softmax over j per row; write normalized P bf16 --
#pragma unroll
  for (int rep = 0; rep < 2; ++rep) {
    int il = wave * 2 + rep;
    float v[6];
    float mx = -1e30f;
#pragma unroll
    for (int c = 0; c < 6; ++c) { v[c] = s_e[il][lane + 64 * c]; mx = fmaxf(mx, v[c]); }
#pragma unroll
    for (int off = 32; off; off >>= 1) mx = fmaxf(mx, __shfl_xor(mx, off));
    float sum = 0.f;
#pragma unroll
    for (int c = 0; c < 6; ++c) { v[c] = __expf(v[c] - mx); sum += v[c]; }
#pragma unroll
    for (int off = 32; off; off >>= 1) sum += __shfl_xor(sum, off);
    float inv = 1.0f / sum;
#pragma unroll
    for (int c = 0; c < 6; ++c) s_pb[il][lane + 64 * c] = f2bf(v[c] * inv);
  }
  __syncthreads();

  // -- phase 3: MFMA aggregation out[12 i][64 f] = P[12][384] @ gr[384][64] --
  if (wave < 4) {
    const int lm = lane & 15, q = lane >> 4;
    const int f0 = wave * 16;
    const ushort_t* Brow = grT + (h * 64 + f0 + lm) * 384;
    f32x4 acc = {0.f, 0.f, 0.f, 0.f};
#pragma unroll
    for (int kc = 0; kc < 12; ++kc) {
      short8 af = *(const short8*)&s_pb[lm][kc * 32 + q * 8];
      short8 bf = *(const short8*)&Brow[kc * 32 + q * 8];
      acc = __builtin_amdgcn_mfma_f32_16x16x32_bf16(af, bf, acc, 0, 0, 0);
    }
    if (q < 3) {                                    // D rows 0..11
#pragma unroll
      for (int r = 0; r < 4; ++r) {
        int i = i0 + q * 4 + r;
        int off = i * HF + h * 64 + f0 + lm;
        float o = acc[r];
        if (LAYER == 0) {
          float oe = (o > 0.f) ? o : (__expf(o) - 1.f);   // ELU
          xcur_out[off] = resid_in[off] + oe;   // fp32 residual for layer 1
        } else {
          f_out[off] = resid_in[off] + o;       // final output, fp32
        }
      }
    }
  }
}

// ---------------------------------------------------------------------------
extern "C" void kernel_launch(void* const* d_in, const int* in_sizes, int n_in,
                              void* d_out, int out_size, void* d_ws, size_t ws_size,
                              hipStream_t stream) {
  const float* x   = (const float*)d_in[0];
  const int*   adj = (const int*)d_in[1];
  const float* Wl0 = (const float*)d_in[2];
  const float* Wr0 = (const float*)d_in[3];
  const float* a0  = (const float*)d_in[4];
  const float* Wl1 = (const float*)d_in[5];
  const float* Wr1 = (const float*)d_in[6];
  const float* a1  = (const float*)d_in[7];
  float* out = (float*)d_out;

  char* ws = (char*)d_ws;
  float*    G    = (float*)   (ws + 0L);            // 1.5 MB (gr half used)
  ushort_t* grT  = (ushort_t*)(ws + (2L << 20));    // 384 KB gr^T bf16
  ushort_t* glb  = (ushort_t*)(ws + (3L << 20));    // 384 KB gl bf16
  u64*      mbits= (u64*)     (ws + (4L << 20));    // 18 KB adjacency bits
  float*    xcur = (float*)   (ws + (5L << 20));    // 768 KB fp32 residual

  gemm_direct<<<dim3(24, 8), 256, 0, stream>>>(x, Wl0, Wr0, G, glb, grT,
                                               adj, mbits);
  attn_fused<0><<<dim3(32, 8), 384, 0, stream>>>(G, glb, grT, mbits, x, a0,
                                                 xcur, nullptr);
  gemm_direct<<<dim3(24, 8), 256, 0, stream>>>(xcur, Wl1, Wr1, G, glb, grT,
                                               nullptr, nullptr);
  attn_fused<1><<<dim3(32, 8), 384, 0, stream>>>(G, glb, grT, mbits, xcur, a1,
                                                 nullptr, out);
}